// Round 8
// baseline (460.858 us; speedup 1.0000x reference)
//
#include <hip/hip_runtime.h>

#define NODES 50000
#define EDGES 600000
#define C     128
#define NGRAPH 64
#define EPSBN 1e-5f
#define SCANB 196   // 196*256 = 50176 >= NODES

typedef short v8s __attribute__((ext_vector_type(8)));
typedef float v4f __attribute__((ext_vector_type(4)));

// ---------------- workspace layout (bytes) ----------------
// zeroed region (one hipMemsetAsync):
#define OFF_DEGCNT 0u          // int[50048]   -> 200192
#define OFF_CURSOR 200192u     // int[50048]   -> 400384
#define OFF_STATS  400384u     // float[768]   -> 403456
#define OFF_PSUM   403456u     // float[8192]  -> 436224
#define ZERO_BYTES 436224u
// non-zeroed:
#define OFF_ROWPTR 436224u     // int[50056]   -> 636448
#define OFF_DINV   636448u     // float[50048] -> 836640
#define OFF_BSUM   836640u     // int[256]     -> 837664
#define OFF_BPACK  837664u     // short[3*16384] -> 935968  (packed bf16 W frags)
#define OFF_EC     935968u     // int2[600064] -> 5736480   (packed edge records)
#define OFF_BUFH   5736480u    // ushort[6400000] (bf16 H) -> 18536480
#define OFF_BUFA   18536480u   // ushort[6400000] (bf16 A) -> 31336480

// fp32 -> bf16 round-to-nearest-even
static __device__ __forceinline__ unsigned short f2bf(float f) {
    unsigned u = __float_as_uint(f);
    u += 0x7fffu + ((u >> 16) & 1u);
    return (unsigned short)(u >> 16);
}
static __device__ __forceinline__ float bflo(unsigned u) { return __uint_as_float(u << 16); }
static __device__ __forceinline__ float bfhi(unsigned u) { return __uint_as_float(u & 0xffff0000u); }
static __device__ __forceinline__ float bf1(unsigned short s) { return __uint_as_float(((unsigned)s) << 16); }

// ---------------- CSR build ----------------
__global__ void deg_kernel(const int* __restrict__ dst, int* __restrict__ degcnt) {
    int e = blockIdx.x * 256 + threadIdx.x;
    if (e < EDGES) atomicAdd(&degcnt[dst[e]], 1);
}

// phase 1: per-block sum of 256 deg entries
__global__ __launch_bounds__(256) void scan1_kernel(const int* __restrict__ degcnt,
                                                    int* __restrict__ bsum) {
    int t = threadIdx.x;
    int i = blockIdx.x * 256 + t;
    int v = (i < NODES) ? degcnt[i] : 0;
    __shared__ int sc[256];
    sc[t] = v; __syncthreads();
    for (int off = 128; off > 0; off >>= 1) {
        if (t < off) sc[t] += sc[t + off];
        __syncthreads();
    }
    if (t == 0) bsum[blockIdx.x] = sc[0];
}

// phase 2 (scan2 folded in): per-block redundant reduce of bsum[0..bid) gives block
// prefix; then block-local inclusive scan of deg; write rowptr & dinv.
__global__ __launch_bounds__(256) void scan3_kernel(const int* __restrict__ degcnt,
                                                    const int* __restrict__ bsum,
                                                    int* __restrict__ rowptr,
                                                    float* __restrict__ dinv) {
    int t = threadIdx.x;
    int bid = blockIdx.x;
    __shared__ int sc[256];
    // prefix = sum(bsum[0..bid))
    int pv = (t < bid) ? bsum[t] : 0;
    sc[t] = pv; __syncthreads();
    for (int off = 128; off > 0; off >>= 1) {
        if (t < off) sc[t] += sc[t + off];
        __syncthreads();
    }
    int prefix = sc[0];
    __syncthreads();
    // local inclusive scan
    int i = bid * 256 + t;
    int v = (i < NODES) ? degcnt[i] : 0;
    sc[t] = v; __syncthreads();
    for (int off = 1; off < 256; off <<= 1) {
        int u = 0; if (t >= off) u = sc[t - off];
        __syncthreads(); sc[t] += u; __syncthreads();
    }
    if (i < NODES) {
        rowptr[i] = prefix + sc[t] - v;  // exclusive
        dinv[i] = (v > 0) ? rsqrtf((float)v) : 0.f;
    }
    if (bid == 0 && t == 0) rowptr[NODES] = EDGES;
}

__global__ void fill_kernel(const int* __restrict__ src, const int* __restrict__ dst,
                            const int* __restrict__ rowptr, int* __restrict__ cursor,
                            const float* __restrict__ dinv,
                            int2* __restrict__ ec) {
    int e = blockIdx.x * 256 + threadIdx.x;
    if (e < EDGES) {
        int s = src[e], d = dst[e];
        int pos = rowptr[d] + atomicAdd(&cursor[d], 1);
        ec[pos] = make_int2(s, __float_as_int(dinv[s] * dinv[d]));
    }
}

// ---------------- W pre-pack: fp32 [128k][128n] -> bf16 B-fragment layout ----------------
__global__ __launch_bounds__(256) void pack_kernel(const float* __restrict__ W0,
                                                   const float* __restrict__ W1,
                                                   const float* __restrict__ W2,
                                                   short* __restrict__ Bp) {
    int id = blockIdx.x * 256 + threadIdx.x;   // 24*256 = 6144 = 3*2048 frags
    int l = id >> 11;
    int f = id & 2047;
    const float* W = (l == 0) ? W0 : (l == 1) ? W1 : W2;
    int lane = f & 63, nbks = f >> 6;
    int nb = nbks >> 2, ks = nbks & 3;
    int q = lane >> 4, n = lane & 15;
    v8s o;
    #pragma unroll
    for (int j = 0; j < 8; j++)
        o[j] = (short)f2bf(W[(ks * 32 + q * 8 + j) * 128 + nb * 16 + n]);
    *(v8s*)&Bp[id * 8] = o;
}

// ---------------- MFMA GEMM: H[64 rows x 128 cols] per block, bf16 in/out ----------------
// finalize folded in: stats!=nullptr -> compute BN scale/shift into LDS at block start.
template<bool A32>
__global__ __launch_bounds__(256) void gemm_kernel(
    const void* __restrict__ Ain, const short* __restrict__ Bpg,
    unsigned short* __restrict__ Hout, const float* __restrict__ stats,
    const float* __restrict__ g, const float* __restrict__ be) {
    __shared__ short Apk[8320];    // 16 segs * 520 shorts
    __shared__ short Bpk[16384];
    __shared__ float sbn[256];
    int t = threadIdx.x;
    int r0 = blockIdx.x * 64;
    if (stats) {
        if (t < 128) {
            float mean = stats[t] * (1.0f / NODES);
            float var = stats[128 + t] * (1.0f / NODES) - mean * mean;
            float sc = g[t] * rsqrtf(var + EPSBN);
            sbn[t] = sc;
            sbn[128 + t] = be[t] - mean * sc;
        }
        __syncthreads();
    }
    // stage B: flat 32 KB copy
    #pragma unroll
    for (int i = 0; i < 8; i++) {
        int c = t + 256 * i;
        *(v8s*)&Bpk[c * 8] = *(const v8s*)&Bpg[c * 8];
    }
    // stage A: 1024 frags, BN+ReLU fused, pack to MFMA A-layout
    #pragma unroll
    for (int i = 0; i < 4; i++) {
        int f = t + 256 * i;
        int row = f >> 4, kf = f & 15;
        int gr = r0 + row;
        float v[8];
        #pragma unroll
        for (int e = 0; e < 8; e++) v[e] = 0.f;
        if (gr < NODES) {
            if (A32) {
                const float* Ap = (const float*)Ain + (size_t)gr * C + kf * 8;
                float4 lo = *(const float4*)Ap;
                float4 hi = *(const float4*)(Ap + 4);
                v[0]=lo.x; v[1]=lo.y; v[2]=lo.z; v[3]=lo.w;
                v[4]=hi.x; v[5]=hi.y; v[6]=hi.z; v[7]=hi.w;
            } else {
                const unsigned short* Ap = (const unsigned short*)Ain + (size_t)gr * C + kf * 8;
                uint4 raw = *(const uint4*)Ap;
                v[0]=bflo(raw.x); v[1]=bfhi(raw.x); v[2]=bflo(raw.y); v[3]=bfhi(raw.y);
                v[4]=bflo(raw.z); v[5]=bfhi(raw.z); v[6]=bflo(raw.w); v[7]=bfhi(raw.w);
            }
        }
        if (stats) {
            #pragma unroll
            for (int e = 0; e < 8; e++) {
                int c = kf * 8 + e;
                v[e] = fmaxf(0.f, fmaf(v[e], sbn[c], sbn[128 + c]));
            }
        }
        v8s af;
        #pragma unroll
        for (int e = 0; e < 8; e++) af[e] = (short)f2bf(v[e]);
        int mb = row >> 4, m = row & 15, ks = kf >> 2, q = kf & 3;
        *(v8s*)&Apk[(mb * 4 + ks) * 520 + (q * 16 + m) * 8] = af;
    }
    __syncthreads();
    int lane = t & 63, mb = t >> 6;
    v4f acc[8];
    #pragma unroll
    for (int nb = 0; nb < 8; nb++) acc[nb] = 0.f;
    #pragma unroll
    for (int ks = 0; ks < 4; ks++) {
        v8s aF = *(const v8s*)&Apk[(mb * 4 + ks) * 520 + lane * 8];
        #pragma unroll
        for (int nb = 0; nb < 8; nb++) {
            v8s bF = *(const v8s*)&Bpk[((nb * 4 + ks) * 64 + lane) * 8];
            acc[nb] = __builtin_amdgcn_mfma_f32_16x16x32_bf16(aF, bF, acc[nb], 0, 0, 0);
        }
    }
    // epilogue: C/D frag -> LDS -> coalesced bf16 store (wave-local region)
    int q = lane >> 4, n = lane & 15;
    #pragma unroll
    for (int nb = 0; nb < 8; nb++) {
        #pragma unroll
        for (int r = 0; r < 4; r++)
            Apk[mb * 2080 + (q * 4 + r) * 128 + nb * 16 + n] = (short)f2bf(acc[nb][r]);
    }
    #pragma unroll
    for (int i = 0; i < 4; i++) {
        int idx = lane + 64 * i;
        int row = idx >> 4, colv = (idx & 15) * 8;
        int gr = r0 + mb * 16 + row;
        if (gr < NODES)
            *(uint4*)&Hout[(size_t)gr * C + colv] = *(const uint4*)&Apk[mb * 2080 + row * 128 + colv];
    }
}

// ---------------- aggregation: channel-split + XCD swizzle ----------------
// 25000 blocks; XCDs 0-3 (blockIdx%8 in 0..3) process channel-half 0, XCDs 4-7 half 1.
// Each wave: one node, 64 channels (half), 16-deep gather pipeline (2 KB in flight).
__global__ __launch_bounds__(256) void agg_kernel(
    const unsigned short* __restrict__ H, const int* __restrict__ rowptr,
    const int2* __restrict__ ec, unsigned short* __restrict__ Aout) {
    int bid = blockIdx.x;
    int xcd = bid & 7;
    int half = xcd >> 2;
    int ord = ((bid >> 3) << 2) + (xcd & 3);     // 0..12499
    int node = (ord << 2) + (threadIdx.x >> 6);  // 4 waves/block
    int lane = threadIdx.x & 63;
    int beg = rowptr[node], end = rowptr[node + 1];
    const unsigned short* Hl = H + (half << 6) + lane;
    float ac = 0.f;
    int i = beg;
    for (; i + 16 <= end; i += 16) {
        int2 e[16]; unsigned short u[16];
        #pragma unroll
        for (int j = 0; j < 16; j++) e[j] = ec[i + j];
        #pragma unroll
        for (int j = 0; j < 16; j++) u[j] = Hl[(size_t)e[j].x * C];
        #pragma unroll
        for (int j = 0; j < 16; j++) ac = fmaf(__int_as_float(e[j].y), bf1(u[j]), ac);
    }
    for (; i + 8 <= end; i += 8) {
        int2 e[8]; unsigned short u[8];
        #pragma unroll
        for (int j = 0; j < 8; j++) e[j] = ec[i + j];
        #pragma unroll
        for (int j = 0; j < 8; j++) u[j] = Hl[(size_t)e[j].x * C];
        #pragma unroll
        for (int j = 0; j < 8; j++) ac = fmaf(__int_as_float(e[j].y), bf1(u[j]), ac);
    }
    for (; i + 4 <= end; i += 4) {
        int2 e[4]; unsigned short u[4];
        #pragma unroll
        for (int j = 0; j < 4; j++) e[j] = ec[i + j];
        #pragma unroll
        for (int j = 0; j < 4; j++) u[j] = Hl[(size_t)e[j].x * C];
        #pragma unroll
        for (int j = 0; j < 4; j++) ac = fmaf(__int_as_float(e[j].y), bf1(u[j]), ac);
    }
    for (; i < end; i++) {
        int2 e = ec[i];
        ac = fmaf(__int_as_float(e.y), bf1(Hl[(size_t)e.x * C]), ac);
    }
    Aout[(size_t)node * C + (half << 6) + lane] = f2bf(ac);
}

// ---------------- BN stats on bf16 activations ----------------
__global__ __launch_bounds__(256) void stats_kernel(const unsigned short* __restrict__ X,
                                                    float* __restrict__ stats) {
    int t = threadIdx.x, lane = t & 63, rg = t >> 6;
    float s0 = 0.f, s1 = 0.f, q0 = 0.f, q1 = 0.f;
    for (int r = blockIdx.x * 4 + rg; r < NODES; r += 1024) {
        unsigned u = *(const unsigned*)&X[(size_t)r * C + lane * 2];
        float x0 = bflo(u), x1 = bfhi(u);
        s0 += x0; s1 += x1;
        q0 = fmaf(x0, x0, q0); q1 = fmaf(x1, x1, q1);
    }
    __shared__ float red[1024];
    red[t] = s0; red[256 + t] = s1; red[512 + t] = q0; red[768 + t] = q1;
    __syncthreads();
    if (t < 64) {
        s0 = red[t] + red[t + 64] + red[t + 128] + red[t + 192];
        s1 = red[256 + t] + red[320 + t] + red[384 + t] + red[448 + t];
        q0 = red[512 + t] + red[576 + t] + red[640 + t] + red[704 + t];
        q1 = red[768 + t] + red[832 + t] + red[896 + t] + red[960 + t];
        atomicAdd(&stats[2 * t], s0);
        atomicAdd(&stats[2 * t + 1], s1);
        atomicAdd(&stats[128 + 2 * t], q0);
        atomicAdd(&stats[128 + 2 * t + 1], q1);
    }
}

// ---------------- pooling (BN2+ReLU fused, finalize folded in), bf16 input -------------
__global__ __launch_bounds__(128) void pool_kernel(const unsigned short* __restrict__ X,
                                                   const int* __restrict__ batch,
                                                   const float* __restrict__ stats,
                                                   const float* __restrict__ g,
                                                   const float* __restrict__ be,
                                                   float* __restrict__ psum) {
    int c = threadIdx.x;
    __shared__ float sbn[256];
    {
        float mean = stats[c] * (1.0f / NODES);
        float var = stats[128 + c] * (1.0f / NODES) - mean * mean;
        float scv = g[c] * rsqrtf(var + EPSBN);
        sbn[c] = scv;
        sbn[128 + c] = be[c] - mean * scv;
    }
    __syncthreads();
    int r0 = blockIdx.x * 128;
    if (r0 >= NODES) return;
    int rend = min(r0 + 128, NODES);
    float sc = sbn[c], sh = sbn[128 + c];
    float acc = 0.f;
    int cur = batch[r0];
    for (int r = r0; r < rend; r++) {
        int gb = batch[r];
        if (gb != cur) { atomicAdd(&psum[cur * C + c], acc); acc = 0.f; cur = gb; }
        float v = bf1(X[(size_t)r * C + c]);
        v = fmaxf(0.f, fmaf(v, sc, sh));
        acc += v;
    }
    atomicAdd(&psum[cur * C + c], acc);
}

// ---------------- head (+ per-graph counts via binary search on sorted batch) -----------
__global__ __launch_bounds__(512) void head_kernel(const float* __restrict__ psum,
                                                   const int* __restrict__ batch,
                                                   const float* __restrict__ Wh,
                                                   const float* __restrict__ bh,
                                                   float* __restrict__ out) {
    __shared__ int sb[65];
    int t = threadIdx.x;
    if (t <= 64) {
        int lo = 0, hi = NODES;
        while (lo < hi) { int m = (lo + hi) >> 1; if (batch[m] < t) lo = m + 1; else hi = m; }
        sb[t] = lo;  // lower_bound(t); sb[64] = NODES
    }
    __syncthreads();
    int g = t >> 3, o = t & 7;
    float inv = 1.0f / fmaxf((float)(sb[g + 1] - sb[g]), 1.0f);
    float acc = 0.f;
    for (int c = 0; c < C; c++) acc = fmaf(psum[g * C + c], Wh[c * 8 + o], acc);
    out[t] = fmaf(acc, inv, bh[o]);
}

extern "C" void kernel_launch(void* const* d_in, const int* in_sizes, int n_in,
                              void* d_out, int out_size, void* d_ws, size_t ws_size,
                              hipStream_t stream) {
    (void)in_sizes; (void)n_in; (void)out_size; (void)ws_size;
    const float* x    = (const float*)d_in[0];
    const int*   ei   = (const int*)d_in[1];      // [2, EDGES]: src then dst
    const int*   batch= (const int*)d_in[2];
    const float* W0   = (const float*)d_in[3];
    const float* g0   = (const float*)d_in[5];
    const float* be0  = (const float*)d_in[6];
    const float* W1   = (const float*)d_in[7];
    const float* g1   = (const float*)d_in[9];
    const float* be1  = (const float*)d_in[10];
    const float* W2   = (const float*)d_in[11];
    const float* g2   = (const float*)d_in[13];
    const float* be2  = (const float*)d_in[14];
    const float* Wh   = (const float*)d_in[15];
    const float* bh   = (const float*)d_in[16];
    float* out = (float*)d_out;

    char* ws = (char*)d_ws;
    int*   degcnt = (int*)(ws + OFF_DEGCNT);
    int*   cursor = (int*)(ws + OFF_CURSOR);
    float* stats  = (float*)(ws + OFF_STATS);
    float* psum   = (float*)(ws + OFF_PSUM);
    int*   rowptr = (int*)(ws + OFF_ROWPTR);
    float* dinv   = (float*)(ws + OFF_DINV);
    int*   bsum   = (int*)(ws + OFF_BSUM);
    short* bpack  = (short*)(ws + OFF_BPACK);
    int2*  ec     = (int2*)(ws + OFF_EC);
    unsigned short* bufH = (unsigned short*)(ws + OFF_BUFH);
    unsigned short* bufA = (unsigned short*)(ws + OFF_BUFA);

    (void)hipMemsetAsync(ws, 0, ZERO_BYTES, stream);

    const int EB = (EDGES + 255) / 256;
    deg_kernel<<<EB, 256, 0, stream>>>(ei + EDGES, degcnt);
    scan1_kernel<<<SCANB, 256, 0, stream>>>(degcnt, bsum);
    scan3_kernel<<<SCANB, 256, 0, stream>>>(degcnt, bsum, rowptr, dinv);
    fill_kernel<<<EB, 256, 0, stream>>>(ei, ei + EDGES, rowptr, cursor, dinv, ec);
    pack_kernel<<<24, 256, 0, stream>>>(W0, W1, W2, bpack);

    const int GB = (NODES + 63) / 64;   // 782
    const int AGB = 25000;              // 12500 node-blocks x 2 channel halves

    // layer 0 (A = fp32 x, no BN)
    gemm_kernel<true><<<GB, 256, 0, stream>>>(x, bpack, bufH, nullptr, nullptr, nullptr);
    agg_kernel<<<AGB, 256, 0, stream>>>(bufH, rowptr, ec, bufA);
    stats_kernel<<<256, 256, 0, stream>>>(bufA, stats + 0);
    // layer 1 (BN0+ReLU fused in staging; finalize folded in)
    gemm_kernel<false><<<GB, 256, 0, stream>>>(bufA, bpack + 16384, bufH, stats + 0, g0, be0);
    agg_kernel<<<AGB, 256, 0, stream>>>(bufH, rowptr, ec, bufA);
    stats_kernel<<<256, 256, 0, stream>>>(bufA, stats + 256);
    // layer 2
    gemm_kernel<false><<<GB, 256, 0, stream>>>(bufA, bpack + 32768, bufH, stats + 256, g1, be1);
    agg_kernel<<<AGB, 256, 0, stream>>>(bufH, rowptr, ec, bufA);
    stats_kernel<<<256, 256, 0, stream>>>(bufA, stats + 512);
    // pool + head (BN2+ReLU+finalize fused into pool; counts via binary search in head)
    pool_kernel<<<(NODES + 127) / 128, 128, 0, stream>>>(bufA, batch, stats + 512, g2, be2, psum);
    head_kernel<<<1, 512, 0, stream>>>(psum, batch, Wh, bh, out);
}

// Round 9
// 413.049 us; speedup vs baseline: 1.1157x; 1.1157x over previous
//
#include <hip/hip_runtime.h>

#define NODES 50000
#define EDGES 600000
#define C     128
#define NGRAPH 64
#define EPSBN 1e-5f
#define SCANB 196   // 196*256 = 50176 >= NODES

typedef short v8s __attribute__((ext_vector_type(8)));
typedef float v4f __attribute__((ext_vector_type(4)));

// ---------------- workspace layout (bytes) ----------------
// zeroed region (one hipMemsetAsync):
#define OFF_DEGCNT 0u          // int[50048]   -> 200192
#define OFF_CURSOR 200192u     // int[50048]   -> 400384
#define OFF_STATS  400384u     // float[768]   -> 403456
#define OFF_PSUM   403456u     // float[8192]  -> 436224
#define ZERO_BYTES 436224u
// non-zeroed:
#define OFF_ROWPTR 436224u     // int[50056]   -> 636448
#define OFF_DINV   636448u     // float[50048] -> 836640
#define OFF_BSUM   836640u     // int[256]     -> 837664
#define OFF_BPACK  837664u     // short[3*16384] -> 935968  (packed bf16 W frags)
#define OFF_EC     935968u     // int2[600064] -> 5736480   (packed edge records)
#define OFF_BUFH   5736480u    // ushort[6400000] (bf16 H) -> 18536480
#define OFF_BUFA   18536480u   // ushort[6400000] (bf16 A) -> 31336480

// fp32 -> bf16 round-to-nearest-even
static __device__ __forceinline__ unsigned short f2bf(float f) {
    unsigned u = __float_as_uint(f);
    u += 0x7fffu + ((u >> 16) & 1u);
    return (unsigned short)(u >> 16);
}
static __device__ __forceinline__ float bflo(unsigned u) { return __uint_as_float(u << 16); }
static __device__ __forceinline__ float bfhi(unsigned u) { return __uint_as_float(u & 0xffff0000u); }
static __device__ __forceinline__ float bf1(unsigned short s) { return __uint_as_float(((unsigned)s) << 16); }

// ---------------- CSR build ----------------
__global__ void deg_kernel(const int* __restrict__ dst, int* __restrict__ degcnt) {
    int e = blockIdx.x * 256 + threadIdx.x;
    if (e < EDGES) atomicAdd(&degcnt[dst[e]], 1);
}

// phase 1: per-block sum of 256 deg entries
__global__ __launch_bounds__(256) void scan1_kernel(const int* __restrict__ degcnt,
                                                    int* __restrict__ bsum) {
    int t = threadIdx.x;
    int i = blockIdx.x * 256 + t;
    int v = (i < NODES) ? degcnt[i] : 0;
    __shared__ int sc[256];
    sc[t] = v; __syncthreads();
    for (int off = 128; off > 0; off >>= 1) {
        if (t < off) sc[t] += sc[t + off];
        __syncthreads();
    }
    if (t == 0) bsum[blockIdx.x] = sc[0];
}

// phase 2 (scan2 folded in): per-block redundant reduce of bsum[0..bid) gives block
// prefix; then block-local inclusive scan of deg; write rowptr & dinv.
__global__ __launch_bounds__(256) void scan3_kernel(const int* __restrict__ degcnt,
                                                    const int* __restrict__ bsum,
                                                    int* __restrict__ rowptr,
                                                    float* __restrict__ dinv) {
    int t = threadIdx.x;
    int bid = blockIdx.x;
    __shared__ int sc[256];
    // prefix = sum(bsum[0..bid))
    int pv = (t < bid) ? bsum[t] : 0;
    sc[t] = pv; __syncthreads();
    for (int off = 128; off > 0; off >>= 1) {
        if (t < off) sc[t] += sc[t + off];
        __syncthreads();
    }
    int prefix = sc[0];
    __syncthreads();
    // local inclusive scan
    int i = bid * 256 + t;
    int v = (i < NODES) ? degcnt[i] : 0;
    sc[t] = v; __syncthreads();
    for (int off = 1; off < 256; off <<= 1) {
        int u = 0; if (t >= off) u = sc[t - off];
        __syncthreads(); sc[t] += u; __syncthreads();
    }
    if (i < NODES) {
        rowptr[i] = prefix + sc[t] - v;  // exclusive
        dinv[i] = (v > 0) ? rsqrtf((float)v) : 0.f;
    }
    if (bid == 0 && t == 0) rowptr[NODES] = EDGES;
}

__global__ void fill_kernel(const int* __restrict__ src, const int* __restrict__ dst,
                            const int* __restrict__ rowptr, int* __restrict__ cursor,
                            const float* __restrict__ dinv,
                            int2* __restrict__ ec) {
    int e = blockIdx.x * 256 + threadIdx.x;
    if (e < EDGES) {
        int s = src[e], d = dst[e];
        int pos = rowptr[d] + atomicAdd(&cursor[d], 1);
        ec[pos] = make_int2(s, __float_as_int(dinv[s] * dinv[d]));
    }
}

// ---------------- W pre-pack: fp32 [128k][128n] -> bf16 B-fragment layout ----------------
__global__ __launch_bounds__(256) void pack_kernel(const float* __restrict__ W0,
                                                   const float* __restrict__ W1,
                                                   const float* __restrict__ W2,
                                                   short* __restrict__ Bp) {
    int id = blockIdx.x * 256 + threadIdx.x;   // 24*256 = 6144 = 3*2048 frags
    int l = id >> 11;
    int f = id & 2047;
    const float* W = (l == 0) ? W0 : (l == 1) ? W1 : W2;
    int lane = f & 63, nbks = f >> 6;
    int nb = nbks >> 2, ks = nbks & 3;
    int q = lane >> 4, n = lane & 15;
    v8s o;
    #pragma unroll
    for (int j = 0; j < 8; j++)
        o[j] = (short)f2bf(W[(ks * 32 + q * 8 + j) * 128 + nb * 16 + n]);
    *(v8s*)&Bp[id * 8] = o;
}

// ---------------- MFMA GEMM: H[64 rows x 128 cols] per block, bf16 in/out ----------------
// finalize folded in: stats!=nullptr -> compute BN scale/shift into LDS at block start.
template<bool A32>
__global__ __launch_bounds__(256) void gemm_kernel(
    const void* __restrict__ Ain, const short* __restrict__ Bpg,
    unsigned short* __restrict__ Hout, const float* __restrict__ stats,
    const float* __restrict__ g, const float* __restrict__ be) {
    __shared__ short Apk[8320];    // 16 segs * 520 shorts
    __shared__ short Bpk[16384];
    __shared__ float sbn[256];
    int t = threadIdx.x;
    int r0 = blockIdx.x * 64;
    if (stats) {
        if (t < 128) {
            float mean = stats[t] * (1.0f / NODES);
            float var = stats[128 + t] * (1.0f / NODES) - mean * mean;
            float sc = g[t] * rsqrtf(var + EPSBN);
            sbn[t] = sc;
            sbn[128 + t] = be[t] - mean * sc;
        }
        __syncthreads();
    }
    // stage B: flat 32 KB copy
    #pragma unroll
    for (int i = 0; i < 8; i++) {
        int c = t + 256 * i;
        *(v8s*)&Bpk[c * 8] = *(const v8s*)&Bpg[c * 8];
    }
    // stage A: 1024 frags, BN+ReLU fused, pack to MFMA A-layout
    #pragma unroll
    for (int i = 0; i < 4; i++) {
        int f = t + 256 * i;
        int row = f >> 4, kf = f & 15;
        int gr = r0 + row;
        float v[8];
        #pragma unroll
        for (int e = 0; e < 8; e++) v[e] = 0.f;
        if (gr < NODES) {
            if (A32) {
                const float* Ap = (const float*)Ain + (size_t)gr * C + kf * 8;
                float4 lo = *(const float4*)Ap;
                float4 hi = *(const float4*)(Ap + 4);
                v[0]=lo.x; v[1]=lo.y; v[2]=lo.z; v[3]=lo.w;
                v[4]=hi.x; v[5]=hi.y; v[6]=hi.z; v[7]=hi.w;
            } else {
                const unsigned short* Ap = (const unsigned short*)Ain + (size_t)gr * C + kf * 8;
                uint4 raw = *(const uint4*)Ap;
                v[0]=bflo(raw.x); v[1]=bfhi(raw.x); v[2]=bflo(raw.y); v[3]=bfhi(raw.y);
                v[4]=bflo(raw.z); v[5]=bfhi(raw.z); v[6]=bflo(raw.w); v[7]=bfhi(raw.w);
            }
        }
        if (stats) {
            #pragma unroll
            for (int e = 0; e < 8; e++) {
                int c = kf * 8 + e;
                v[e] = fmaxf(0.f, fmaf(v[e], sbn[c], sbn[128 + c]));
            }
        }
        v8s af;
        #pragma unroll
        for (int e = 0; e < 8; e++) af[e] = (short)f2bf(v[e]);
        int mb = row >> 4, m = row & 15, ks = kf >> 2, q = kf & 3;
        *(v8s*)&Apk[(mb * 4 + ks) * 520 + (q * 16 + m) * 8] = af;
    }
    __syncthreads();
    int lane = t & 63, mb = t >> 6;
    v4f acc[8];
    #pragma unroll
    for (int nb = 0; nb < 8; nb++) acc[nb] = 0.f;
    #pragma unroll
    for (int ks = 0; ks < 4; ks++) {
        v8s aF = *(const v8s*)&Apk[(mb * 4 + ks) * 520 + lane * 8];
        #pragma unroll
        for (int nb = 0; nb < 8; nb++) {
            v8s bF = *(const v8s*)&Bpk[((nb * 4 + ks) * 64 + lane) * 8];
            acc[nb] = __builtin_amdgcn_mfma_f32_16x16x32_bf16(aF, bF, acc[nb], 0, 0, 0);
        }
    }
    // epilogue: C/D frag -> LDS -> coalesced bf16 store (wave-local region)
    int q = lane >> 4, n = lane & 15;
    #pragma unroll
    for (int nb = 0; nb < 8; nb++) {
        #pragma unroll
        for (int r = 0; r < 4; r++)
            Apk[mb * 2080 + (q * 4 + r) * 128 + nb * 16 + n] = (short)f2bf(acc[nb][r]);
    }
    #pragma unroll
    for (int i = 0; i < 4; i++) {
        int idx = lane + 64 * i;
        int row = idx >> 4, colv = (idx & 15) * 8;
        int gr = r0 + mb * 16 + row;
        if (gr < NODES)
            *(uint4*)&Hout[(size_t)gr * C + colv] = *(const uint4*)&Apk[mb * 2080 + row * 128 + colv];
    }
}

// ---------------- aggregation: wave/node, full 128-ch row, packed records, 8-way MLP ------
__global__ __launch_bounds__(256) void agg_kernel(
    const unsigned short* __restrict__ H, const int* __restrict__ rowptr,
    const int2* __restrict__ ec, unsigned short* __restrict__ Aout) {
    int wid = (blockIdx.x * 256 + threadIdx.x) >> 6;
    int lane = threadIdx.x & 63;
    if (wid >= NODES) return;
    int beg = rowptr[wid], end = rowptr[wid + 1];
    const unsigned short* Hl = H + lane * 2;
    float ax = 0.f, ay = 0.f;
    int i = beg;
    for (; i + 8 <= end; i += 8) {
        int2 e[8]; unsigned u[8];
        #pragma unroll
        for (int j = 0; j < 8; j++) e[j] = ec[i + j];
        #pragma unroll
        for (int j = 0; j < 8; j++) u[j] = *(const unsigned*)&Hl[(size_t)e[j].x * C];
        #pragma unroll
        for (int j = 0; j < 8; j++) {
            float w = __int_as_float(e[j].y);
            ax = fmaf(w, bflo(u[j]), ax); ay = fmaf(w, bfhi(u[j]), ay);
        }
    }
    for (; i + 4 <= end; i += 4) {
        int2 e[4]; unsigned u[4];
        #pragma unroll
        for (int j = 0; j < 4; j++) e[j] = ec[i + j];
        #pragma unroll
        for (int j = 0; j < 4; j++) u[j] = *(const unsigned*)&Hl[(size_t)e[j].x * C];
        #pragma unroll
        for (int j = 0; j < 4; j++) {
            float w = __int_as_float(e[j].y);
            ax = fmaf(w, bflo(u[j]), ax); ay = fmaf(w, bfhi(u[j]), ay);
        }
    }
    for (; i < end; i++) {
        int2 e = ec[i];
        unsigned u = *(const unsigned*)&Hl[(size_t)e.x * C];
        float w = __int_as_float(e.y);
        ax = fmaf(w, bflo(u), ax); ay = fmaf(w, bfhi(u), ay);
    }
    unsigned o = ((unsigned)f2bf(ay) << 16) | (unsigned)f2bf(ax);
    *(unsigned*)&Aout[(size_t)wid * C + lane * 2] = o;
}

// ---------------- BN stats on bf16 activations ----------------
__global__ __launch_bounds__(256) void stats_kernel(const unsigned short* __restrict__ X,
                                                    float* __restrict__ stats) {
    int t = threadIdx.x, lane = t & 63, rg = t >> 6;
    float s0 = 0.f, s1 = 0.f, q0 = 0.f, q1 = 0.f;
    for (int r = blockIdx.x * 4 + rg; r < NODES; r += 1024) {
        unsigned u = *(const unsigned*)&X[(size_t)r * C + lane * 2];
        float x0 = bflo(u), x1 = bfhi(u);
        s0 += x0; s1 += x1;
        q0 = fmaf(x0, x0, q0); q1 = fmaf(x1, x1, q1);
    }
    __shared__ float red[1024];
    red[t] = s0; red[256 + t] = s1; red[512 + t] = q0; red[768 + t] = q1;
    __syncthreads();
    if (t < 64) {
        s0 = red[t] + red[t + 64] + red[t + 128] + red[t + 192];
        s1 = red[256 + t] + red[320 + t] + red[384 + t] + red[448 + t];
        q0 = red[512 + t] + red[576 + t] + red[640 + t] + red[704 + t];
        q1 = red[768 + t] + red[832 + t] + red[896 + t] + red[960 + t];
        atomicAdd(&stats[2 * t], s0);
        atomicAdd(&stats[2 * t + 1], s1);
        atomicAdd(&stats[128 + 2 * t], q0);
        atomicAdd(&stats[128 + 2 * t + 1], q1);
    }
}

// ---------------- pooling (BN2+ReLU fused, finalize folded in), bf16 input -------------
__global__ __launch_bounds__(128) void pool_kernel(const unsigned short* __restrict__ X,
                                                   const int* __restrict__ batch,
                                                   const float* __restrict__ stats,
                                                   const float* __restrict__ g,
                                                   const float* __restrict__ be,
                                                   float* __restrict__ psum) {
    int c = threadIdx.x;
    __shared__ float sbn[256];
    {
        float mean = stats[c] * (1.0f / NODES);
        float var = stats[128 + c] * (1.0f / NODES) - mean * mean;
        float scv = g[c] * rsqrtf(var + EPSBN);
        sbn[c] = scv;
        sbn[128 + c] = be[c] - mean * scv;
    }
    __syncthreads();
    int r0 = blockIdx.x * 128;
    if (r0 >= NODES) return;
    int rend = min(r0 + 128, NODES);
    float sc = sbn[c], sh = sbn[128 + c];
    float acc = 0.f;
    int cur = batch[r0];
    for (int r = r0; r < rend; r++) {
        int gb = batch[r];
        if (gb != cur) { atomicAdd(&psum[cur * C + c], acc); acc = 0.f; cur = gb; }
        float v = bf1(X[(size_t)r * C + c]);
        v = fmaxf(0.f, fmaf(v, sc, sh));
        acc += v;
    }
    atomicAdd(&psum[cur * C + c], acc);
}

// ---------------- head (+ per-graph counts via binary search on sorted batch) -----------
__global__ __launch_bounds__(512) void head_kernel(const float* __restrict__ psum,
                                                   const int* __restrict__ batch,
                                                   const float* __restrict__ Wh,
                                                   const float* __restrict__ bh,
                                                   float* __restrict__ out) {
    __shared__ int sb[65];
    int t = threadIdx.x;
    if (t <= 64) {
        int lo = 0, hi = NODES;
        while (lo < hi) { int m = (lo + hi) >> 1; if (batch[m] < t) lo = m + 1; else hi = m; }
        sb[t] = lo;  // lower_bound(t); sb[64] = NODES
    }
    __syncthreads();
    int g = t >> 3, o = t & 7;
    float inv = 1.0f / fmaxf((float)(sb[g + 1] - sb[g]), 1.0f);
    float acc = 0.f;
    for (int c = 0; c < C; c++) acc = fmaf(psum[g * C + c], Wh[c * 8 + o], acc);
    out[t] = fmaf(acc, inv, bh[o]);
}

extern "C" void kernel_launch(void* const* d_in, const int* in_sizes, int n_in,
                              void* d_out, int out_size, void* d_ws, size_t ws_size,
                              hipStream_t stream) {
    (void)in_sizes; (void)n_in; (void)out_size; (void)ws_size;
    const float* x    = (const float*)d_in[0];
    const int*   ei   = (const int*)d_in[1];      // [2, EDGES]: src then dst
    const int*   batch= (const int*)d_in[2];
    const float* W0   = (const float*)d_in[3];
    const float* g0   = (const float*)d_in[5];
    const float* be0  = (const float*)d_in[6];
    const float* W1   = (const float*)d_in[7];
    const float* g1   = (const float*)d_in[9];
    const float* be1  = (const float*)d_in[10];
    const float* W2   = (const float*)d_in[11];
    const float* g2   = (const float*)d_in[13];
    const float* be2  = (const float*)d_in[14];
    const float* Wh   = (const float*)d_in[15];
    const float* bh   = (const float*)d_in[16];
    float* out = (float*)d_out;

    char* ws = (char*)d_ws;
    int*   degcnt = (int*)(ws + OFF_DEGCNT);
    int*   cursor = (int*)(ws + OFF_CURSOR);
    float* stats  = (float*)(ws + OFF_STATS);
    float* psum   = (float*)(ws + OFF_PSUM);
    int*   rowptr = (int*)(ws + OFF_ROWPTR);
    float* dinv   = (float*)(ws + OFF_DINV);
    int*   bsum   = (int*)(ws + OFF_BSUM);
    short* bpack  = (short*)(ws + OFF_BPACK);
    int2*  ec     = (int2*)(ws + OFF_EC);
    unsigned short* bufH = (unsigned short*)(ws + OFF_BUFH);
    unsigned short* bufA = (unsigned short*)(ws + OFF_BUFA);

    (void)hipMemsetAsync(ws, 0, ZERO_BYTES, stream);

    const int EB = (EDGES + 255) / 256;
    deg_kernel<<<EB, 256, 0, stream>>>(ei + EDGES, degcnt);
    scan1_kernel<<<SCANB, 256, 0, stream>>>(degcnt, bsum);
    scan3_kernel<<<SCANB, 256, 0, stream>>>(degcnt, bsum, rowptr, dinv);
    fill_kernel<<<EB, 256, 0, stream>>>(ei, ei + EDGES, rowptr, cursor, dinv, ec);
    pack_kernel<<<24, 256, 0, stream>>>(W0, W1, W2, bpack);

    const int GB = (NODES + 63) / 64;            // 782
    const int AGB = (NODES * 64 + 255) / 256;    // 12500

    // layer 0 (A = fp32 x, no BN)
    gemm_kernel<true><<<GB, 256, 0, stream>>>(x, bpack, bufH, nullptr, nullptr, nullptr);
    agg_kernel<<<AGB, 256, 0, stream>>>(bufH, rowptr, ec, bufA);
    stats_kernel<<<256, 256, 0, stream>>>(bufA, stats + 0);
    // layer 1 (BN0+ReLU fused in staging; finalize folded in)
    gemm_kernel<false><<<GB, 256, 0, stream>>>(bufA, bpack + 16384, bufH, stats + 0, g0, be0);
    agg_kernel<<<AGB, 256, 0, stream>>>(bufH, rowptr, ec, bufA);
    stats_kernel<<<256, 256, 0, stream>>>(bufA, stats + 256);
    // layer 2
    gemm_kernel<false><<<GB, 256, 0, stream>>>(bufA, bpack + 32768, bufH, stats + 256, g1, be1);
    agg_kernel<<<AGB, 256, 0, stream>>>(bufH, rowptr, ec, bufA);
    stats_kernel<<<256, 256, 0, stream>>>(bufA, stats + 512);
    // pool + head (BN2+ReLU+finalize fused into pool; counts via binary search in head)
    pool_kernel<<<(NODES + 127) / 128, 128, 0, stream>>>(bufA, batch, stats + 512, g2, be2, psum);
    head_kernel<<<1, 512, 0, stream>>>(psum, batch, Wh, bh, out);
}

// Round 10
// 408.586 us; speedup vs baseline: 1.1279x; 1.0109x over previous
//
#include <hip/hip_runtime.h>

#define NODES 50000
#define EDGES 600000
#define C     128
#define NGRAPH 64
#define EPSBN 1e-5f
#define SCANB 196   // 196*256 = 50176 >= NODES

typedef short v8s __attribute__((ext_vector_type(8)));
typedef float v4f __attribute__((ext_vector_type(4)));

// ---------------- workspace layout (bytes) ----------------
// zeroed region (one hipMemsetAsync):
#define OFF_DEGCNT 0u          // int[50048]   -> 200192
#define OFF_CURSOR 200192u     // int[50048]   -> 400384
#define OFF_STATS  400384u     // float[768]   -> 403456
#define OFF_PSUM   403456u     // float[8192]  -> 436224
#define ZERO_BYTES 436224u
// non-zeroed:
#define OFF_ROWPTR 436224u     // int[50056]   -> 636448
#define OFF_DINV   636448u     // float[50048] -> 836640
#define OFF_BSUM   836640u     // int[256]     -> 837664
#define OFF_BPACK  837664u     // short[3*16384] -> 935968  (packed bf16 W frags)
#define OFF_EC     935968u     // int2[600064] -> 5736480   (packed edge records)
#define OFF_BUFH   5736480u    // ushort[6400000] (bf16 H) -> 18536480
#define OFF_BUFA   18536480u   // ushort[6400000] (bf16 A) -> 31336480

// fp32 -> bf16 round-to-nearest-even
static __device__ __forceinline__ unsigned short f2bf(float f) {
    unsigned u = __float_as_uint(f);
    u += 0x7fffu + ((u >> 16) & 1u);
    return (unsigned short)(u >> 16);
}
static __device__ __forceinline__ float bflo(unsigned u) { return __uint_as_float(u << 16); }
static __device__ __forceinline__ float bfhi(unsigned u) { return __uint_as_float(u & 0xffff0000u); }
static __device__ __forceinline__ float bf1(unsigned short s) { return __uint_as_float(((unsigned)s) << 16); }

// ---------------- CSR build ----------------
// 4 edges/thread via int4 (EDGES % 4 == 0)
__global__ void deg_kernel(const int* __restrict__ dst, int* __restrict__ degcnt) {
    int e4 = blockIdx.x * 256 + threadIdx.x;
    if (e4 < EDGES / 4) {
        int4 d = *(const int4*)&dst[e4 * 4];
        atomicAdd(&degcnt[d.x], 1);
        atomicAdd(&degcnt[d.y], 1);
        atomicAdd(&degcnt[d.z], 1);
        atomicAdd(&degcnt[d.w], 1);
    }
}

// phase 1: per-block sum of 256 deg entries
__global__ __launch_bounds__(256) void scan1_kernel(const int* __restrict__ degcnt,
                                                    int* __restrict__ bsum) {
    int t = threadIdx.x;
    int i = blockIdx.x * 256 + t;
    int v = (i < NODES) ? degcnt[i] : 0;
    __shared__ int sc[256];
    sc[t] = v; __syncthreads();
    for (int off = 128; off > 0; off >>= 1) {
        if (t < off) sc[t] += sc[t + off];
        __syncthreads();
    }
    if (t == 0) bsum[blockIdx.x] = sc[0];
}

// phase 2 (scan2 folded in): per-block redundant reduce of bsum[0..bid) gives block
// prefix; then block-local inclusive scan of deg; write rowptr & dinv.
__global__ __launch_bounds__(256) void scan3_kernel(const int* __restrict__ degcnt,
                                                    const int* __restrict__ bsum,
                                                    int* __restrict__ rowptr,
                                                    float* __restrict__ dinv) {
    int t = threadIdx.x;
    int bid = blockIdx.x;
    __shared__ int sc[256];
    // prefix = sum(bsum[0..bid))
    int pv = (t < bid) ? bsum[t] : 0;
    sc[t] = pv; __syncthreads();
    for (int off = 128; off > 0; off >>= 1) {
        if (t < off) sc[t] += sc[t + off];
        __syncthreads();
    }
    int prefix = sc[0];
    __syncthreads();
    // local inclusive scan
    int i = bid * 256 + t;
    int v = (i < NODES) ? degcnt[i] : 0;
    sc[t] = v; __syncthreads();
    for (int off = 1; off < 256; off <<= 1) {
        int u = 0; if (t >= off) u = sc[t - off];
        __syncthreads(); sc[t] += u; __syncthreads();
    }
    if (i < NODES) {
        rowptr[i] = prefix + sc[t] - v;  // exclusive
        dinv[i] = (v > 0) ? rsqrtf((float)v) : 0.f;
    }
    if (bid == 0 && t == 0) rowptr[NODES] = EDGES;
}

// 2 edges/thread via int2 (EDGES % 2 == 0)
__global__ void fill_kernel(const int* __restrict__ src, const int* __restrict__ dst,
                            const int* __restrict__ rowptr, int* __restrict__ cursor,
                            const float* __restrict__ dinv,
                            int2* __restrict__ ec) {
    int e2 = blockIdx.x * 256 + threadIdx.x;
    if (e2 < EDGES / 2) {
        int2 s = *(const int2*)&src[e2 * 2];
        int2 d = *(const int2*)&dst[e2 * 2];
        float w0 = dinv[s.x] * dinv[d.x];
        float w1 = dinv[s.y] * dinv[d.y];
        int p0 = rowptr[d.x] + atomicAdd(&cursor[d.x], 1);
        ec[p0] = make_int2(s.x, __float_as_int(w0));
        int p1 = rowptr[d.y] + atomicAdd(&cursor[d.y], 1);
        ec[p1] = make_int2(s.y, __float_as_int(w1));
    }
}

// ---------------- W pre-pack: fp32 [128k][128n] -> bf16 B-fragment layout ----------------
__global__ __launch_bounds__(256) void pack_kernel(const float* __restrict__ W0,
                                                   const float* __restrict__ W1,
                                                   const float* __restrict__ W2,
                                                   short* __restrict__ Bp) {
    int id = blockIdx.x * 256 + threadIdx.x;   // 24*256 = 6144 = 3*2048 frags
    int l = id >> 11;
    int f = id & 2047;
    const float* W = (l == 0) ? W0 : (l == 1) ? W1 : W2;
    int lane = f & 63, nbks = f >> 6;
    int nb = nbks >> 2, ks = nbks & 3;
    int q = lane >> 4, n = lane & 15;
    v8s o;
    #pragma unroll
    for (int j = 0; j < 8; j++)
        o[j] = (short)f2bf(W[(ks * 32 + q * 8 + j) * 128 + nb * 16 + n]);
    *(v8s*)&Bp[id * 8] = o;
}

// ---------------- MFMA GEMM: H[64 rows x 128 cols] per block, bf16 in/out ----------------
// finalize folded in: stats!=nullptr -> compute BN scale/shift into LDS at block start.
template<bool A32>
__global__ __launch_bounds__(256) void gemm_kernel(
    const void* __restrict__ Ain, const short* __restrict__ Bpg,
    unsigned short* __restrict__ Hout, const float* __restrict__ stats,
    const float* __restrict__ g, const float* __restrict__ be) {
    __shared__ short Apk[8320];    // 16 segs * 520 shorts
    __shared__ short Bpk[16384];
    __shared__ float sbn[256];
    int t = threadIdx.x;
    int r0 = blockIdx.x * 64;
    if (stats) {
        if (t < 128) {
            float mean = stats[t] * (1.0f / NODES);
            float var = stats[128 + t] * (1.0f / NODES) - mean * mean;
            float sc = g[t] * rsqrtf(var + EPSBN);
            sbn[t] = sc;
            sbn[128 + t] = be[t] - mean * sc;
        }
        __syncthreads();
    }
    // stage B: flat 32 KB copy
    #pragma unroll
    for (int i = 0; i < 8; i++) {
        int c = t + 256 * i;
        *(v8s*)&Bpk[c * 8] = *(const v8s*)&Bpg[c * 8];
    }
    // stage A: 1024 frags, BN+ReLU fused, pack to MFMA A-layout
    #pragma unroll
    for (int i = 0; i < 4; i++) {
        int f = t + 256 * i;
        int row = f >> 4, kf = f & 15;
        int gr = r0 + row;
        float v[8];
        #pragma unroll
        for (int e = 0; e < 8; e++) v[e] = 0.f;
        if (gr < NODES) {
            if (A32) {
                const float* Ap = (const float*)Ain + (size_t)gr * C + kf * 8;
                float4 lo = *(const float4*)Ap;
                float4 hi = *(const float4*)(Ap + 4);
                v[0]=lo.x; v[1]=lo.y; v[2]=lo.z; v[3]=lo.w;
                v[4]=hi.x; v[5]=hi.y; v[6]=hi.z; v[7]=hi.w;
            } else {
                const unsigned short* Ap = (const unsigned short*)Ain + (size_t)gr * C + kf * 8;
                uint4 raw = *(const uint4*)Ap;
                v[0]=bflo(raw.x); v[1]=bfhi(raw.x); v[2]=bflo(raw.y); v[3]=bfhi(raw.y);
                v[4]=bflo(raw.z); v[5]=bfhi(raw.z); v[6]=bflo(raw.w); v[7]=bfhi(raw.w);
            }
        }
        if (stats) {
            #pragma unroll
            for (int e = 0; e < 8; e++) {
                int c = kf * 8 + e;
                v[e] = fmaxf(0.f, fmaf(v[e], sbn[c], sbn[128 + c]));
            }
        }
        v8s af;
        #pragma unroll
        for (int e = 0; e < 8; e++) af[e] = (short)f2bf(v[e]);
        int mb = row >> 4, m = row & 15, ks = kf >> 2, q = kf & 3;
        *(v8s*)&Apk[(mb * 4 + ks) * 520 + (q * 16 + m) * 8] = af;
    }
    __syncthreads();
    int lane = t & 63, mb = t >> 6;
    v4f acc[8];
    #pragma unroll
    for (int nb = 0; nb < 8; nb++) acc[nb] = 0.f;
    #pragma unroll
    for (int ks = 0; ks < 4; ks++) {
        v8s aF = *(const v8s*)&Apk[(mb * 4 + ks) * 520 + lane * 8];
        #pragma unroll
        for (int nb = 0; nb < 8; nb++) {
            v8s bF = *(const v8s*)&Bpk[((nb * 4 + ks) * 64 + lane) * 8];
            acc[nb] = __builtin_amdgcn_mfma_f32_16x16x32_bf16(aF, bF, acc[nb], 0, 0, 0);
        }
    }
    // epilogue: C/D frag -> LDS -> coalesced bf16 store (wave-local region)
    int q = lane >> 4, n = lane & 15;
    #pragma unroll
    for (int nb = 0; nb < 8; nb++) {
        #pragma unroll
        for (int r = 0; r < 4; r++)
            Apk[mb * 2080 + (q * 4 + r) * 128 + nb * 16 + n] = (short)f2bf(acc[nb][r]);
    }
    #pragma unroll
    for (int i = 0; i < 4; i++) {
        int idx = lane + 64 * i;
        int row = idx >> 4, colv = (idx & 15) * 8;
        int gr = r0 + mb * 16 + row;
        if (gr < NODES)
            *(uint4*)&Hout[(size_t)gr * C + colv] = *(const uint4*)&Apk[mb * 2080 + row * 128 + colv];
    }
}

// ---------------- aggregation: wave/node, full 128-ch row, packed records, 8-way MLP ------
__global__ __launch_bounds__(256) void agg_kernel(
    const unsigned short* __restrict__ H, const int* __restrict__ rowptr,
    const int2* __restrict__ ec, unsigned short* __restrict__ Aout) {
    int wid = (blockIdx.x * 256 + threadIdx.x) >> 6;
    int lane = threadIdx.x & 63;
    if (wid >= NODES) return;
    int beg = rowptr[wid], end = rowptr[wid + 1];
    const unsigned short* Hl = H + lane * 2;
    float ax = 0.f, ay = 0.f;
    int i = beg;
    for (; i + 8 <= end; i += 8) {
        int2 e[8]; unsigned u[8];
        #pragma unroll
        for (int j = 0; j < 8; j++) e[j] = ec[i + j];
        #pragma unroll
        for (int j = 0; j < 8; j++) u[j] = *(const unsigned*)&Hl[(size_t)e[j].x * C];
        #pragma unroll
        for (int j = 0; j < 8; j++) {
            float w = __int_as_float(e[j].y);
            ax = fmaf(w, bflo(u[j]), ax); ay = fmaf(w, bfhi(u[j]), ay);
        }
    }
    for (; i + 4 <= end; i += 4) {
        int2 e[4]; unsigned u[4];
        #pragma unroll
        for (int j = 0; j < 4; j++) e[j] = ec[i + j];
        #pragma unroll
        for (int j = 0; j < 4; j++) u[j] = *(const unsigned*)&Hl[(size_t)e[j].x * C];
        #pragma unroll
        for (int j = 0; j < 4; j++) {
            float w = __int_as_float(e[j].y);
            ax = fmaf(w, bflo(u[j]), ax); ay = fmaf(w, bfhi(u[j]), ay);
        }
    }
    for (; i < end; i++) {
        int2 e = ec[i];
        unsigned u = *(const unsigned*)&Hl[(size_t)e.x * C];
        float w = __int_as_float(e.y);
        ax = fmaf(w, bflo(u), ax); ay = fmaf(w, bfhi(u), ay);
    }
    unsigned o = ((unsigned)f2bf(ay) << 16) | (unsigned)f2bf(ax);
    *(unsigned*)&Aout[(size_t)wid * C + lane * 2] = o;
}

// ---------------- BN stats on bf16 activations (512 blocks) ----------------
__global__ __launch_bounds__(256) void stats_kernel(const unsigned short* __restrict__ X,
                                                    float* __restrict__ stats) {
    int t = threadIdx.x, lane = t & 63, rg = t >> 6;
    float s0 = 0.f, s1 = 0.f, q0 = 0.f, q1 = 0.f;
    for (int r = blockIdx.x * 4 + rg; r < NODES; r += 2048) {
        unsigned u = *(const unsigned*)&X[(size_t)r * C + lane * 2];
        float x0 = bflo(u), x1 = bfhi(u);
        s0 += x0; s1 += x1;
        q0 = fmaf(x0, x0, q0); q1 = fmaf(x1, x1, q1);
    }
    __shared__ float red[1024];
    red[t] = s0; red[256 + t] = s1; red[512 + t] = q0; red[768 + t] = q1;
    __syncthreads();
    if (t < 64) {
        s0 = red[t] + red[t + 64] + red[t + 128] + red[t + 192];
        s1 = red[256 + t] + red[320 + t] + red[384 + t] + red[448 + t];
        q0 = red[512 + t] + red[576 + t] + red[640 + t] + red[704 + t];
        q1 = red[768 + t] + red[832 + t] + red[896 + t] + red[960 + t];
        atomicAdd(&stats[2 * t], s0);
        atomicAdd(&stats[2 * t + 1], s1);
        atomicAdd(&stats[128 + 2 * t], q0);
        atomicAdd(&stats[128 + 2 * t + 1], q1);
    }
}

// ---------------- pooling (BN2+ReLU fused, finalize folded in), bf16 input -------------
// 32 rows/block -> 1563 blocks (~12 waves/CU) instead of 391x128-serial-row chain.
#define POOLROWS 32
__global__ __launch_bounds__(128) void pool_kernel(const unsigned short* __restrict__ X,
                                                   const int* __restrict__ batch,
                                                   const float* __restrict__ stats,
                                                   const float* __restrict__ g,
                                                   const float* __restrict__ be,
                                                   float* __restrict__ psum) {
    int c = threadIdx.x;
    __shared__ float sbn[256];
    {
        float mean = stats[c] * (1.0f / NODES);
        float var = stats[128 + c] * (1.0f / NODES) - mean * mean;
        float scv = g[c] * rsqrtf(var + EPSBN);
        sbn[c] = scv;
        sbn[128 + c] = be[c] - mean * scv;
    }
    __syncthreads();
    int r0 = blockIdx.x * POOLROWS;
    if (r0 >= NODES) return;
    int rend = min(r0 + POOLROWS, NODES);
    float sc = sbn[c], sh = sbn[128 + c];
    float acc = 0.f;
    int cur = batch[r0];
    for (int r = r0; r < rend; r++) {
        int gb = batch[r];
        if (gb != cur) { atomicAdd(&psum[cur * C + c], acc); acc = 0.f; cur = gb; }
        float v = bf1(X[(size_t)r * C + c]);
        v = fmaxf(0.f, fmaf(v, sc, sh));
        acc += v;
    }
    atomicAdd(&psum[cur * C + c], acc);
}

// ---------------- head (+ per-graph counts via binary search on sorted batch) -----------
__global__ __launch_bounds__(512) void head_kernel(const float* __restrict__ psum,
                                                   const int* __restrict__ batch,
                                                   const float* __restrict__ Wh,
                                                   const float* __restrict__ bh,
                                                   float* __restrict__ out) {
    __shared__ int sb[65];
    int t = threadIdx.x;
    if (t <= 64) {
        int lo = 0, hi = NODES;
        while (lo < hi) { int m = (lo + hi) >> 1; if (batch[m] < t) lo = m + 1; else hi = m; }
        sb[t] = lo;  // lower_bound(t); sb[64] = NODES
    }
    __syncthreads();
    int g = t >> 3, o = t & 7;
    float inv = 1.0f / fmaxf((float)(sb[g + 1] - sb[g]), 1.0f);
    float acc = 0.f;
    for (int c = 0; c < C; c++) acc = fmaf(psum[g * C + c], Wh[c * 8 + o], acc);
    out[t] = fmaf(acc, inv, bh[o]);
}

extern "C" void kernel_launch(void* const* d_in, const int* in_sizes, int n_in,
                              void* d_out, int out_size, void* d_ws, size_t ws_size,
                              hipStream_t stream) {
    (void)in_sizes; (void)n_in; (void)out_size; (void)ws_size;
    const float* x    = (const float*)d_in[0];
    const int*   ei   = (const int*)d_in[1];      // [2, EDGES]: src then dst
    const int*   batch= (const int*)d_in[2];
    const float* W0   = (const float*)d_in[3];
    const float* g0   = (const float*)d_in[5];
    const float* be0  = (const float*)d_in[6];
    const float* W1   = (const float*)d_in[7];
    const float* g1   = (const float*)d_in[9];
    const float* be1  = (const float*)d_in[10];
    const float* W2   = (const float*)d_in[11];
    const float* g2   = (const float*)d_in[13];
    const float* be2  = (const float*)d_in[14];
    const float* Wh   = (const float*)d_in[15];
    const float* bh   = (const float*)d_in[16];
    float* out = (float*)d_out;

    char* ws = (char*)d_ws;
    int*   degcnt = (int*)(ws + OFF_DEGCNT);
    int*   cursor = (int*)(ws + OFF_CURSOR);
    float* stats  = (float*)(ws + OFF_STATS);
    float* psum   = (float*)(ws + OFF_PSUM);
    int*   rowptr = (int*)(ws + OFF_ROWPTR);
    float* dinv   = (float*)(ws + OFF_DINV);
    int*   bsum   = (int*)(ws + OFF_BSUM);
    short* bpack  = (short*)(ws + OFF_BPACK);
    int2*  ec     = (int2*)(ws + OFF_EC);
    unsigned short* bufH = (unsigned short*)(ws + OFF_BUFH);
    unsigned short* bufA = (unsigned short*)(ws + OFF_BUFA);

    (void)hipMemsetAsync(ws, 0, ZERO_BYTES, stream);

    deg_kernel<<<(EDGES / 4 + 255) / 256, 256, 0, stream>>>(ei + EDGES, degcnt);
    scan1_kernel<<<SCANB, 256, 0, stream>>>(degcnt, bsum);
    scan3_kernel<<<SCANB, 256, 0, stream>>>(degcnt, bsum, rowptr, dinv);
    fill_kernel<<<(EDGES / 2 + 255) / 256, 256, 0, stream>>>(ei, ei + EDGES, rowptr, cursor, dinv, ec);
    pack_kernel<<<24, 256, 0, stream>>>(W0, W1, W2, bpack);

    const int GB = (NODES + 63) / 64;            // 782
    const int AGB = (NODES * 64 + 255) / 256;    // 12500

    // layer 0 (A = fp32 x, no BN)
    gemm_kernel<true><<<GB, 256, 0, stream>>>(x, bpack, bufH, nullptr, nullptr, nullptr);
    agg_kernel<<<AGB, 256, 0, stream>>>(bufH, rowptr, ec, bufA);
    stats_kernel<<<512, 256, 0, stream>>>(bufA, stats + 0);
    // layer 1 (BN0+ReLU fused in staging; finalize folded in)
    gemm_kernel<false><<<GB, 256, 0, stream>>>(bufA, bpack + 16384, bufH, stats + 0, g0, be0);
    agg_kernel<<<AGB, 256, 0, stream>>>(bufH, rowptr, ec, bufA);
    stats_kernel<<<512, 256, 0, stream>>>(bufA, stats + 256);
    // layer 2
    gemm_kernel<false><<<GB, 256, 0, stream>>>(bufA, bpack + 32768, bufH, stats + 256, g1, be1);
    agg_kernel<<<AGB, 256, 0, stream>>>(bufH, rowptr, ec, bufA);
    stats_kernel<<<512, 256, 0, stream>>>(bufA, stats + 512);
    // pool + head (BN2+ReLU+finalize fused into pool; counts via binary search in head)
    pool_kernel<<<(NODES + POOLROWS - 1) / POOLROWS, 128, 0, stream>>>(bufA, batch, stats + 512, g2, be2, psum);
    head_kernel<<<1, 512, 0, stream>>>(psum, batch, Wh, bh, out);
}